// Round 15
// baseline (606.753 us; speedup 1.0000x reference)
//
#include <hip/hip_runtime.h>

typedef __bf16 bf16;
typedef __attribute__((ext_vector_type(8))) __bf16 bf16x8;
typedef __attribute__((ext_vector_type(4))) __bf16 bf16x4;
typedef __attribute__((ext_vector_type(4))) float f32x4;

#define N_TOK 16384
#define DMODEL 1024
#define FDIM 4096
#define NHEAD 16

// ---------------------------------------------------------------- helpers
__device__ __forceinline__ void gload_lds16(const bf16* g, bf16* l) {
  __builtin_amdgcn_global_load_lds(
      (const __attribute__((address_space(1))) void*)g,
      (__attribute__((address_space(3))) void*)l,
      16, 0, 0);
}

// gelu(x) = 0.5x(1+tanh(z)) = x / (1 + exp(-2z)),  z = 0.79788456(x + 0.044715x^3)
__device__ __forceinline__ float gelu_fast(float x) {
  float z2 = 1.5957691216057308f * (x + 0.044715f * x * x * x);
  return x / (1.0f + __expf(-z2));
}

// ---------------------------------------------------------------- fp32 -> bf16 copy
__global__ __launch_bounds__(256) void cvt_copy(const float* __restrict__ x,
                                                bf16* __restrict__ y) {
  size_t i = ((size_t)blockIdx.x * 256 + threadIdx.x) * 8;
  float4 a = *(const float4*)(x + i);
  float4 b = *(const float4*)(x + i + 4);
  bf16x8 o;
  o[0] = (bf16)a.x; o[1] = (bf16)a.y; o[2] = (bf16)a.z; o[3] = (bf16)a.w;
  o[4] = (bf16)b.x; o[5] = (bf16)b.y; o[6] = (bf16)b.z; o[7] = (bf16)b.w;
  *(bf16x8*)(y + i) = o;
}

// ---------------------------------------------------------------- convert+transpose
__global__ void convt(const float* __restrict__ src, bf16* __restrict__ dst,
                      int R, int C) {
  __shared__ float tile[32][33];
  int c0 = blockIdx.x * 32, r0 = blockIdx.y * 32;
  int tx = threadIdx.x, ty = threadIdx.y;
#pragma unroll
  for (int i = 0; i < 4; ++i)
    tile[ty * 4 + i][tx] = src[(size_t)(r0 + ty * 4 + i) * C + c0 + tx];
  __syncthreads();
#pragma unroll
  for (int i = 0; i < 4; ++i)
    dst[(size_t)(c0 + ty * 4 + i) * R + r0 + tx] = (bf16)tile[tx][ty * 4 + i];
}

// batched 1024x1024 convt: blockIdx.z selects matrix (saves 3 launch gaps)
__global__ void convt4(const float* __restrict__ s0, const float* __restrict__ s1,
                       const float* __restrict__ s2, const float* __restrict__ s3,
                       bf16* __restrict__ d0, bf16* __restrict__ d1,
                       bf16* __restrict__ d2, bf16* __restrict__ d3) {
  __shared__ float tile[32][33];
  const int z = blockIdx.z;                 // wave-uniform -> s_cselect
  const float* src = z == 0 ? s0 : z == 1 ? s1 : z == 2 ? s2 : s3;
  bf16* dst = z == 0 ? d0 : z == 1 ? d1 : z == 2 ? d2 : d3;
  int c0 = blockIdx.x * 32, r0 = blockIdx.y * 32;
  int tx = threadIdx.x, ty = threadIdx.y;
#pragma unroll
  for (int i = 0; i < 4; ++i)
    tile[ty * 4 + i][tx] = src[(size_t)(r0 + ty * 4 + i) * 1024 + c0 + tx];
  __syncthreads();
#pragma unroll
  for (int i = 0; i < 4; ++i)
    dst[(size_t)(c0 + ty * 4 + i) * 1024 + r0 + tx] = (bf16)tile[tx][ty * 4 + i];
}

// ---------------------------------------------------------------- 2-phase BM=256 GEMM
// C[M][N] = A[M][K] @ BT[N][K]^T + bias (+res) (+gelu); output bf16.
// BM=256, BN=256, BK=64. 512 threads, 8 waves (2Mx4N), wave tile 128x64.
// Merged 2-phase schedule, R15 stage-split (m201-style earlier issue):
//   read aLo(8)+bF0(4)+bF1(4); lgkmcnt(0); barrier;   <- ALL cb reads done
//   stage B(t+2) into cb;  MFMA m-lo x n0-3 (32);     <- B-stage overlaps both MFMA blocks
//   read aHi(8); lgkmcnt(0); barrier;                 <- all sA[cb] reads done
//   stage A(t+2) into cb;  MFMA m-hi x n0-3 (32); vmcnt(8); barrier.
// Ledger: at tile end, outstanding = t+1's 8 (oldest) + t+2's 8; vmcnt(8)
// completes t+1 exactly, leaves t+2 in flight (T4 never-drain). Stage
// targets are provably fully-read (explicit lgkmcnt before each barrier).
// 0-conflict XOR swizzle (chunk^=row&7).
template <int RES, int GELU, int SPLIT3>   // RES: 0 none, 1 fp32, 2 bf16
__global__ __launch_bounds__(512) void gemm_f(
    const bf16* __restrict__ A, const bf16* __restrict__ BT,
    const float* __restrict__ bias, const float* __restrict__ bias2,
    const float* __restrict__ bias3, const float* __restrict__ resf,
    const bf16* __restrict__ resb, bf16* __restrict__ C,
    bf16* __restrict__ C2, bf16* __restrict__ C3,
    int M, int N, int K) {
  __shared__ alignas(16) bf16 sA[2][256 * 64];
  __shared__ alignas(16) bf16 sB[2][256 * 64];

  const int tid = threadIdx.x;
  const int lane = tid & 63, wv = tid >> 6;
  const int wr = wv >> 2, wc = wv & 3;       // 2 x 4 wave grid
  const int r16 = lane & 15, hk = lane >> 4;

  const int nbn = N >> 8;
  const int cpx = gridDim.x >> 3;            // grid % 8 == 0
  const int swz = ((int)blockIdx.x & 7) * cpx + ((int)blockIdx.x >> 3);
  const int row0 = (swz / nbn) << 8, col0 = (swz % nbn) << 8;

  const bf16* Ab = A + (size_t)row0 * K;
  const bf16* Bb = BT + (size_t)col0 * K;

  const bf16* gA[4];
  const bf16* gB[4];
#pragma unroll
  for (int l = 0; l < 4; ++l) {
    int g = l * 512 + tid, r = g >> 3, p = g & 7;
    gA[l] = Ab + (size_t)r * K + ((p ^ (r & 7)) << 3);
    gB[l] = Bb + (size_t)r * K + ((p ^ (r & 7)) << 3);
  }

  auto stageA4 = [&](int buf, int kt) {
    const size_t ko = (size_t)kt << 6;
#pragma unroll
    for (int l = 0; l < 4; ++l)
      gload_lds16(gA[l] + ko, &sA[buf][(l * 512 + tid) * 8]);
  };
  auto stageB4 = [&](int buf, int kt) {
    const size_t ko = (size_t)kt << 6;
#pragma unroll
    for (int l = 0; l < 4; ++l)
      gload_lds16(gB[l] + ko, &sB[buf][(l * 512 + tid) * 8]);
  };
  auto frag = [&](const bf16* s, int row, int kc) -> bf16x8 {
    return *(const bf16x8*)(s + row * 64 + (kc ^ ((row & 7) * 8)));
  };

  f32x4 acc[8][4] = {};
  bf16x8 aF[4][2], bF0[2][2], bF1[2][2];

  const int nt = K >> 6;
  stageA4(0, 0); stageB4(0, 0);
  stageA4(1, 1); stageB4(1, 1);
  asm volatile("s_waitcnt vmcnt(8)" ::: "memory");   // tile 0 done, tile 1 in flight
  __builtin_amdgcn_s_barrier();

  for (int kt = 0; kt < nt; ++kt) {
    const int cb = kt & 1;
    const bf16* sa = &sA[cb][0];
    const bf16* sb = &sB[cb][0];
    const bool pf = (kt + 2 < nt);

    // ---- top reads: aLo + all B; force completion before barrier ----
#pragma unroll
    for (int m = 0; m < 4; ++m)
#pragma unroll
      for (int ks = 0; ks < 2; ++ks)
        aF[m][ks] = frag(sa, wr * 128 + m * 16 + r16, ks * 32 + hk * 8);
#pragma unroll
    for (int n = 0; n < 2; ++n)
#pragma unroll
      for (int ks = 0; ks < 2; ++ks) {
        bF0[n][ks] = frag(sb, wc * 64 + n * 16 + r16, ks * 32 + hk * 8);
        bF1[n][ks] = frag(sb, wc * 64 + (2 + n) * 16 + r16, ks * 32 + hk * 8);
      }
    asm volatile("s_waitcnt lgkmcnt(0)" ::: "memory");
    __builtin_amdgcn_s_barrier();

    // ---- stage B(t+2) into cb: sB[cb] fully read by ALL waves ----
    if (pf) stageB4(cb, kt + 2);

    // ---- MFMA m-lo x n0-3 (32) ----
    __builtin_amdgcn_s_setprio(1);
#pragma unroll
    for (int ks = 0; ks < 2; ++ks)
#pragma unroll
      for (int m = 0; m < 4; ++m)
#pragma unroll
        for (int n = 0; n < 2; ++n) {
          acc[m][n]     = __builtin_amdgcn_mfma_f32_16x16x32_bf16(bF0[n][ks], aF[m][ks], acc[m][n], 0, 0, 0);
          acc[m][2 + n] = __builtin_amdgcn_mfma_f32_16x16x32_bf16(bF1[n][ks], aF[m][ks], acc[m][2 + n], 0, 0, 0);
        }
    __builtin_amdgcn_s_setprio(0);

    // ---- read aHi (reuse aF); force completion before barrier ----
#pragma unroll
    for (int m = 0; m < 4; ++m)
#pragma unroll
      for (int ks = 0; ks < 2; ++ks)
        aF[m][ks] = frag(sa, wr * 128 + (4 + m) * 16 + r16, ks * 32 + hk * 8);
    asm volatile("s_waitcnt lgkmcnt(0)" ::: "memory");
    __builtin_amdgcn_s_barrier();

    // ---- stage A(t+2) into cb: sA[cb] fully read by ALL waves ----
    if (pf) stageA4(cb, kt + 2);

    // ---- MFMA m-hi x n0-3 (32) ----
    __builtin_amdgcn_s_setprio(1);
#pragma unroll
    for (int ks = 0; ks < 2; ++ks)
#pragma unroll
      for (int m = 0; m < 4; ++m)
#pragma unroll
        for (int n = 0; n < 2; ++n) {
          acc[4 + m][n]     = __builtin_amdgcn_mfma_f32_16x16x32_bf16(bF0[n][ks], aF[m][ks], acc[4 + m][n], 0, 0, 0);
          acc[4 + m][2 + n] = __builtin_amdgcn_mfma_f32_16x16x32_bf16(bF1[n][ks], aF[m][ks], acc[4 + m][2 + n], 0, 0, 0);
        }
    __builtin_amdgcn_s_setprio(0);
    if (pf) {
      asm volatile("s_waitcnt vmcnt(8)" ::: "memory");  // t+1 done; t+2 in flight
    } else if (kt + 1 < nt) {
      asm volatile("s_waitcnt vmcnt(0)" ::: "memory");
    }
    __builtin_amdgcn_s_barrier();
  }

  // ---- epilogue ----
  bf16* Cp = C;
  const float* bp = bias;
  int ldc = N, colb = col0;
  if constexpr (SPLIT3) {
    int grp = col0 >> 10;
    Cp = grp == 0 ? C : (grp == 1 ? C2 : C3);
    bp = grp == 0 ? bias : (grp == 1 ? bias2 : bias3);
    ldc = 1024;
    colb = col0 & 1023;
  }
#pragma unroll
  for (int m = 0; m < 8; ++m) {
    int row = row0 + wr * 128 + m * 16 + r16;
#pragma unroll
    for (int n = 0; n < 4; ++n) {
      int col = colb + wc * 64 + n * 16 + hk * 4;
      f32x4 b4 = *(const f32x4*)&bp[col];
      f32x4 v;
#pragma unroll
      for (int r = 0; r < 4; ++r) v[r] = acc[m][n][r] + b4[r];
      if (RES == 1) {
        f32x4 rr = *(const f32x4*)&resf[(size_t)row * ldc + col];
#pragma unroll
        for (int r = 0; r < 4; ++r) v[r] += rr[r];
      }
      if (RES == 2) {
        bf16x4 rb = *(const bf16x4*)&resb[(size_t)row * ldc + col];
#pragma unroll
        for (int r = 0; r < 4; ++r) v[r] += (float)rb[r];
      }
      bf16x4 o;
#pragma unroll
      for (int r = 0; r < 4; ++r) {
        float x = v[r];
        if (GELU) x = gelu_fast(x);
        o[r] = (bf16)x;
      }
      *(bf16x4*)&Cp[(size_t)row * ldc + col] = o;
    }
  }
}

// ---------------------------------------------------------------- 2-phase BM=128 GEMM (deep-K / small-B)
// BM=128, BN=256, BK=64; 3 LDS buffers (144 KiB); vmcnt(6)/tile completes
// t+1, leaves t+2 in flight. RES: 1 fp32 residual (Wo), 2 bf16 (FFN-down).
template <int RES>
__global__ __launch_bounds__(512) void gemm_d(
    const bf16* __restrict__ A, const bf16* __restrict__ BT,
    const float* __restrict__ bias, const float* __restrict__ resf,
    const bf16* __restrict__ resb, bf16* __restrict__ C,
    int M, int N, int K) {
  __shared__ alignas(16) bf16 sA[3][128 * 64];   // 48 KiB
  __shared__ alignas(16) bf16 sB[3][256 * 64];   // 96 KiB

  const int tid = threadIdx.x;
  const int lane = tid & 63, wv = tid >> 6;
  const int wr = wv >> 2, wc = wv & 3;
  const int r16 = lane & 15, hk = lane >> 4;

  const int nbn = N >> 8;
  const int cpx = gridDim.x >> 3;
  const int swz = ((int)blockIdx.x & 7) * cpx + ((int)blockIdx.x >> 3);
  const int row0 = (swz / nbn) * 128, col0 = (swz % nbn) << 8;

  const bf16* Ab = A + (size_t)row0 * K;
  const bf16* Bb = BT + (size_t)col0 * K;

  const bf16* gA[2];
  const bf16* gB[4];
#pragma unroll
  for (int l = 0; l < 2; ++l) {
    int g = l * 512 + tid, r = g >> 3, p = g & 7;
    gA[l] = Ab + (size_t)r * K + ((p ^ (r & 7)) << 3);
  }
#pragma unroll
  for (int l = 0; l < 4; ++l) {
    int g = l * 512 + tid, r = g >> 3, p = g & 7;
    gB[l] = Bb + (size_t)r * K + ((p ^ (r & 7)) << 3);
  }

  auto stage = [&](int buf, int kt) {
    const size_t ko = (size_t)kt << 6;
#pragma unroll
    for (int l = 0; l < 2; ++l)
      gload_lds16(gA[l] + ko, &sA[buf][(l * 512 + tid) * 8]);
#pragma unroll
    for (int l = 0; l < 4; ++l)
      gload_lds16(gB[l] + ko, &sB[buf][(l * 512 + tid) * 8]);
  };
  auto frag = [&](const bf16* s, int row, int kc) -> bf16x8 {
    return *(const bf16x8*)(s + row * 64 + (kc ^ ((row & 7) * 8)));
  };

  f32x4 acc[4][4] = {};
  bf16x8 aF[4][2], bF0[2][2], bF1[2][2];

  const int nt = K >> 6;
  stage(0, 0);
  stage(1, 1);
  asm volatile("s_waitcnt vmcnt(6)" ::: "memory");
  __builtin_amdgcn_s_barrier();

  int cur = 0;
  for (int kt = 0; kt < nt; ++kt) {
    const bf16* sa = &sA[cur][0];
    const bf16* sb = &sB[cur][0];
    const int nx2 = (cur + 2 >= 3) ? cur - 1 : cur + 2;   // (kt+2)%3
    const bool pf = (kt + 2 < nt);

#pragma unroll
    for (int m = 0; m < 4; ++m)
#pragma unroll
      for (int ks = 0; ks < 2; ++ks)
        aF[m][ks] = frag(sa, wr * 64 + m * 16 + r16, ks * 32 + hk * 8);
#pragma unroll
    for (int n = 0; n < 2; ++n)
#pragma unroll
      for (int ks = 0; ks < 2; ++ks)
        bF0[n][ks] = frag(sb, wc * 64 + n * 16 + r16, ks * 32 + hk * 8);
    __builtin_amdgcn_s_barrier();
    __builtin_amdgcn_s_setprio(1);
#pragma unroll
    for (int ks = 0; ks < 2; ++ks)
#pragma unroll
      for (int m = 0; m < 4; ++m)
#pragma unroll
        for (int n = 0; n < 2; ++n)
          acc[m][n] = __builtin_amdgcn_mfma_f32_16x16x32_bf16(bF0[n][ks], aF[m][ks], acc[m][n], 0, 0, 0);
    __builtin_amdgcn_s_setprio(0);
    __builtin_amdgcn_s_barrier();

#pragma unroll
    for (int n = 0; n < 2; ++n)
#pragma unroll
      for (int ks = 0; ks < 2; ++ks)
        bF1[n][ks] = frag(sb, wc * 64 + (2 + n) * 16 + r16, ks * 32 + hk * 8);
    if (pf) stage(nx2, kt + 2);
    __builtin_amdgcn_s_barrier();
    __builtin_amdgcn_s_setprio(1);
#pragma unroll
    for (int ks = 0; ks < 2; ++ks)
#pragma unroll
      for (int m = 0; m < 4; ++m)
#pragma unroll
        for (int n = 0; n < 2; ++n)
          acc[m][2 + n] = __builtin_amdgcn_mfma_f32_16x16x32_bf16(bF1[n][ks], aF[m][ks], acc[m][2 + n], 0, 0, 0);
    __builtin_amdgcn_s_setprio(0);
    if (pf) {
      asm volatile("s_waitcnt vmcnt(6)" ::: "memory");
    } else if (kt + 1 < nt) {
      asm volatile("s_waitcnt vmcnt(0)" ::: "memory");
    }
    __builtin_amdgcn_s_barrier();
    cur = (cur + 1 == 3) ? 0 : cur + 1;
  }

#pragma unroll
  for (int m = 0; m < 4; ++m) {
    int row = row0 + wr * 64 + m * 16 + r16;
#pragma unroll
    for (int n = 0; n < 4; ++n) {
      int col = col0 + wc * 64 + n * 16 + hk * 4;
      f32x4 b4 = *(const f32x4*)&bias[col];
      f32x4 v;
#pragma unroll
      for (int r = 0; r < 4; ++r) v[r] = acc[m][n][r] + b4[r];
      if (RES == 1) {
        f32x4 rr = *(const f32x4*)&resf[(size_t)row * N + col];
#pragma unroll
        for (int r = 0; r < 4; ++r) v[r] += rr[r];
      }
      if (RES == 2) {
        bf16x4 rb = *(const bf16x4*)&resb[(size_t)row * N + col];
#pragma unroll
        for (int r = 0; r < 4; ++r) v[r] += (float)rb[r];
      }
      bf16x4 o;
#pragma unroll
      for (int r = 0; r < 4; ++r) o[r] = (bf16)v[r];
      *(bf16x4*)&C[(size_t)row * N + col] = o;
    }
  }
}

// ---------------------------------------------------------------- attention
// one block per (b,h); L=64, dh=64. ctx may alias q.
__global__ __launch_bounds__(256) void attn_k(
    const bf16* q, const bf16* __restrict__ k,
    const bf16* __restrict__ v, const float* __restrict__ rel,
    bf16* ctx) {
  __shared__ alignas(16) bf16 lQ[64 * 64];
  __shared__ alignas(16) bf16 lK[64 * 64];
  __shared__ alignas(16) bf16 lVt[64 * 64];
  __shared__ alignas(16) bf16 lP[4][16 * 64];
  __shared__ float lrel[128];

  const int bh = blockIdx.x;
  const int b = bh >> 4, h = bh & 15;
  const int tid = threadIdx.x;
  const size_t base = (size_t)(b * 64) * DMODEL + h * 64;

#pragma unroll
  for (int i = 0; i < 2; ++i) {
    int j = (tid >> 3) + i * 32;
    int d0 = (tid & 7) * 8;
    *(bf16x8*)&lQ[j * 64 + d0] = *(const bf16x8*)(q + base + (size_t)j * DMODEL + d0);
    *(bf16x8*)&lK[j * 64 + d0] = *(const bf16x8*)(k + base + (size_t)j * DMODEL + d0);
    bf16x8 vvv = *(const bf16x8*)(v + base + (size_t)j * DMODEL + d0);
#pragma unroll
    for (int u = 0; u < 8; ++u) lVt[(d0 + u) * 64 + j] = vvv[u];
  }
  if (tid < 127) lrel[tid] = rel[h * 127 + tid];
  __syncthreads();

  const int lane = tid & 63, w = tid >> 6;
  const int r16 = lane & 15, hk = lane >> 4;

  f32x4 s[4] = {};
#pragma unroll
  for (int dstep = 0; dstep < 2; ++dstep) {
    bf16x8 aq = *(const bf16x8*)&lQ[(w * 16 + r16) * 64 + dstep * 32 + hk * 8];
#pragma unroll
    for (int n = 0; n < 4; ++n) {
      bf16x8 bk_ = *(const bf16x8*)&lK[(n * 16 + r16) * 64 + dstep * 32 + hk * 8];
      s[n] = __builtin_amdgcn_mfma_f32_16x16x32_bf16(aq, bk_, s[n], 0, 0, 0);
    }
  }

  float p[16];
#pragma unroll
  for (int n = 0; n < 4; ++n)
#pragma unroll
    for (int r = 0; r < 4; ++r) {
      int i = w * 16 + hk * 4 + r;
      int j = n * 16 + r16;
      p[n * 4 + r] = s[n][r] * 0.125f + lrel[i - j + 63];
    }
#pragma unroll
  for (int r = 0; r < 4; ++r) {
    float m = fmaxf(fmaxf(p[r], p[4 + r]), fmaxf(p[8 + r], p[12 + r]));
#pragma unroll
    for (int off = 1; off < 16; off <<= 1) m = fmaxf(m, __shfl_xor(m, off));
    float sum = 0.f;
#pragma unroll
    for (int n = 0; n < 4; ++n) {
      p[n * 4 + r] = __expf(p[n * 4 + r] - m);
      sum += p[n * 4 + r];
    }
#pragma unroll
    for (int off = 1; off < 16; off <<= 1) sum += __shfl_xor(sum, off);
    float inv = 1.0f / sum;
#pragma unroll
    for (int n = 0; n < 4; ++n) p[n * 4 + r] *= inv;
  }
#pragma unroll
  for (int n = 0; n < 4; ++n)
#pragma unroll
    for (int r = 0; r < 4; ++r)
      lP[w][(hk * 4 + r) * 64 + n * 16 + r16] = (bf16)p[n * 4 + r];
  __syncthreads();

  f32x4 o[4] = {};
#pragma unroll
  for (int ks = 0; ks < 2; ++ks) {
    bf16x8 ap = *(const bf16x8*)&lP[w][r16 * 64 + ks * 32 + hk * 8];
#pragma unroll
    for (int n = 0; n < 4; ++n) {
      bf16x8 bv_ = *(const bf16x8*)&lVt[(n * 16 + r16) * 64 + ks * 32 + hk * 8];
      o[n] = __builtin_amdgcn_mfma_f32_16x16x32_bf16(ap, bv_, o[n], 0, 0, 0);
    }
  }
#pragma unroll
  for (int n = 0; n < 4; ++n)
#pragma unroll
    for (int r = 0; r < 4; ++r) {
      int trow = b * 64 + w * 16 + hk * 4 + r;
      ctx[(size_t)trow * DMODEL + h * 64 + n * 16 + r16] = (bf16)o[n][r];
    }
}

// ---------------------------------------------------------------- layernorm
template <int F32OUT>
__global__ __launch_bounds__(256) void layernorm_k(
    const bf16* __restrict__ x, const float* __restrict__ g,
    const float* __restrict__ be, bf16* __restrict__ ob,
    float* __restrict__ of) {
  int row = blockIdx.x * 4 + (threadIdx.x >> 6);
  int lane = threadIdx.x & 63;
  const bf16* xr = x + (size_t)row * DMODEL + lane * 16;
  bf16x8 v0 = *(const bf16x8*)xr;
  bf16x8 v1 = *(const bf16x8*)(xr + 8);
  float f[16];
#pragma unroll
  for (int j = 0; j < 8; ++j) { f[j] = (float)v0[j]; f[8 + j] = (float)v1[j]; }
  float s = 0.f, sq = 0.f;
#pragma unroll
  for (int j = 0; j < 16; ++j) { s += f[j]; sq += f[j] * f[j]; }
#pragma unroll
  for (int off = 1; off < 64; off <<= 1) {
    s += __shfl_xor(s, off);
    sq += __shfl_xor(sq, off);
  }
  float mean = s * (1.0f / DMODEL);
  float var = sq * (1.0f / DMODEL) - mean * mean;
  float rstd = rsqrtf(var + 1e-5f);
  const float* gp = g + lane * 16;
  const float* bp = be + lane * 16;
  if (F32OUT) {
    float* op = of + (size_t)row * DMODEL + lane * 16;
#pragma unroll
    for (int j = 0; j < 16; ++j)
      op[j] = (f[j] - mean) * rstd * gp[j] + bp[j];
  } else {
    bf16x8 o0, o1;
#pragma unroll
    for (int j = 0; j < 8; ++j) {
      o0[j] = (bf16)((f[j] - mean) * rstd * gp[j] + bp[j]);
      o1[j] = (bf16)((f[8 + j] - mean) * rstd * gp[8 + j] + bp[8 + j]);
    }
    bf16* op = ob + (size_t)row * DMODEL + lane * 16;
    *(bf16x8*)op = o0;
    *(bf16x8*)(op + 8) = o1;
  }
}

// ---------------------------------------------------------------- launch
extern "C" void kernel_launch(void* const* d_in, const int* in_sizes, int n_in,
                              void* d_out, int out_size, void* d_ws, size_t ws_size,
                              hipStream_t stream) {
  (void)in_sizes; (void)n_in; (void)out_size;
  const float* src = (const float*)d_in[0];
  const float* Wq  = (const float*)d_in[1];
  const float* bq  = (const float*)d_in[2];
  const float* Wk  = (const float*)d_in[3];
  const float* bk  = (const float*)d_in[4];
  const float* Wv  = (const float*)d_in[5];
  const float* bv  = (const float*)d_in[6];
  const float* Wo  = (const float*)d_in[7];
  const float* bo  = (const float*)d_in[8];
  const float* rel = (const float*)d_in[9];
  const float* W1  = (const float*)d_in[10];
  const float* b1  = (const float*)d_in[11];
  const float* W2  = (const float*)d_in[12];
  const float* b2  = (const float*)d_in[13];
  const float* g1  = (const float*)d_in[14];
  const float* be1 = (const float*)d_in[15];
  const float* g2  = (const float*)d_in[16];
  const float* be2 = (const float*)d_in[17];

  // ws plan: REGION0 = ws[0:64MiB] (srcb+qb -> hbuf -> lnout);
  // weights ws[64:88MiB] (WqT/WkT/WvT contiguous => fused QKV B matrix);
  // y2 in ws[88:120MiB] when ws_size allows, else d_out + copy-out.
  char* ws = (char*)d_ws;
  const size_t MiB = 1ull << 20;
  bf16* srcb = (bf16*)(ws + 0 * MiB);
  bf16* qb   = (bf16*)(ws + 32 * MiB);
  bf16* WqT  = (bf16*)(ws + 64 * MiB);   // [3072][1024] fused: Wq|Wk|Wv
  bf16* WkT  = (bf16*)(ws + 66 * MiB);
  bf16* WvT  = (bf16*)(ws + 68 * MiB);
  bf16* WoT  = (bf16*)(ws + 70 * MiB);
  bf16* W1T  = (bf16*)(ws + 72 * MiB);
  bf16* W2T  = (bf16*)(ws + 80 * MiB);
  bf16* hbuf = (bf16*)(ws + 0 * MiB);
  float* lnout = (float*)(ws + 0 * MiB);
  bf16* kb = (bf16*)d_out;
  bf16* vb = (bf16*)((char*)d_out + 32 * MiB);
  bf16* y1 = kb;
  bf16* xb = vb;
  const bool bigws = (ws_size >= 121 * MiB);
  bf16* y2 = bigws ? (bf16*)(ws + 88 * MiB) : kb;

  cvt_copy<<<(N_TOK * DMODEL) / 2048, 256, 0, stream>>>(src, srcb);
  dim3 tb(32, 8);
  convt4<<<dim3(32, 32, 4), tb, 0, stream>>>(Wq, Wk, Wv, Wo, WqT, WkT, WvT, WoT);
  convt<<<dim3(128, 32), tb, 0, stream>>>(W1, W1T, 1024, 4096);
  convt<<<dim3(32, 128), tb, 0, stream>>>(W2, W2T, 4096, 1024);

  // fused QKV: one GEMM, N=3072 (WqT/WkT/WvT contiguous), split outputs
  const int gQKV3 = (N_TOK / 256) * (3072 / 256);   // 64*12 = 768
  gemm_f<0, 0, 1><<<gQKV3, 512, 0, stream>>>(
      srcb, WqT, bq, bk, bv, nullptr, nullptr, qb, kb, vb, N_TOK, 3072, DMODEL);

  attn_k<<<256 * NHEAD, 256, 0, stream>>>(qb, kb, vb, rel, qb);

  // y1 = ctx @ Wo + bo + src (fp32 residual); Wo B-panel (2 MiB) is
  // L2-resident so BM=128 gemm_d has no re-fetch penalty.
  const int gWo = (N_TOK / 128) * (DMODEL / 256);   // 128*4 = 512
  gemm_d<1><<<gWo, 512, 0, stream>>>(qb, WoT, bo, src, nullptr, y1, N_TOK, DMODEL, DMODEL);
  // x = LN1(y1) -> DO1
  layernorm_k<0><<<N_TOK / 4, 256, 0, stream>>>(y1, g1, be1, xb, nullptr);

  // FFN in 2 chunks of 8192 rows; h (8192x4096 bf16 = 64 MiB) in REGION0
  const int CH = 8192;
  const int gF1 = (CH / 256) * (FDIM / 256);     // 32*16 = 512
  const int gF2 = (CH / 128) * (DMODEL / 256);   // 64*4  = 256
  for (int c = 0; c < 2; ++c) {
    const bf16* xc = xb + (size_t)c * CH * DMODEL;
    bf16* yc = y2 + (size_t)c * CH * DMODEL;
    gemm_f<0, 1, 0><<<gF1, 512, 0, stream>>>(
        xc, W1T, b1, nullptr, nullptr, nullptr, nullptr, hbuf, nullptr, nullptr, CH, FDIM, DMODEL);
    gemm_d<2><<<gF2, 512, 0, stream>>>(hbuf, W2T, b2, nullptr, xc, yc, CH, DMODEL, FDIM);
  }
  if (bigws) {
    layernorm_k<1><<<N_TOK / 4, 256, 0, stream>>>(y2, g2, be2, nullptr, (float*)d_out);
  } else {
    layernorm_k<1><<<N_TOK / 4, 256, 0, stream>>>(y2, g2, be2, nullptr, lnout);
    hipMemcpyAsync(d_out, lnout, (size_t)N_TOK * DMODEL * 4, hipMemcpyDeviceToDevice, stream);
  }
}

// Round 16
// 597.139 us; speedup vs baseline: 1.0161x; 1.0161x over previous
//
#include <hip/hip_runtime.h>

typedef __bf16 bf16;
typedef __attribute__((ext_vector_type(8))) __bf16 bf16x8;
typedef __attribute__((ext_vector_type(4))) __bf16 bf16x4;
typedef __attribute__((ext_vector_type(4))) float f32x4;

#define N_TOK 16384
#define DMODEL 1024
#define FDIM 4096
#define NHEAD 16

// ---------------------------------------------------------------- helpers
__device__ __forceinline__ void gload_lds16(const bf16* g, bf16* l) {
  __builtin_amdgcn_global_load_lds(
      (const __attribute__((address_space(1))) void*)g,
      (__attribute__((address_space(3))) void*)l,
      16, 0, 0);
}

// gelu(x) = 0.5x(1+tanh(z)) = x / (1 + exp(-2z)),  z = 0.79788456(x + 0.044715x^3)
__device__ __forceinline__ float gelu_fast(float x) {
  float z2 = 1.5957691216057308f * (x + 0.044715f * x * x * x);
  return x / (1.0f + __expf(-z2));
}

// ---------------------------------------------------------------- fp32 -> bf16 copy
__global__ __launch_bounds__(256) void cvt_copy(const float* __restrict__ x,
                                                bf16* __restrict__ y) {
  size_t i = ((size_t)blockIdx.x * 256 + threadIdx.x) * 8;
  float4 a = *(const float4*)(x + i);
  float4 b = *(const float4*)(x + i + 4);
  bf16x8 o;
  o[0] = (bf16)a.x; o[1] = (bf16)a.y; o[2] = (bf16)a.z; o[3] = (bf16)a.w;
  o[4] = (bf16)b.x; o[5] = (bf16)b.y; o[6] = (bf16)b.z; o[7] = (bf16)b.w;
  *(bf16x8*)(y + i) = o;
}

// ---------------------------------------------------------------- convert+transpose
__global__ void convt(const float* __restrict__ src, bf16* __restrict__ dst,
                      int R, int C) {
  __shared__ float tile[32][33];
  int c0 = blockIdx.x * 32, r0 = blockIdx.y * 32;
  int tx = threadIdx.x, ty = threadIdx.y;
#pragma unroll
  for (int i = 0; i < 4; ++i)
    tile[ty * 4 + i][tx] = src[(size_t)(r0 + ty * 4 + i) * C + c0 + tx];
  __syncthreads();
#pragma unroll
  for (int i = 0; i < 4; ++i)
    dst[(size_t)(c0 + ty * 4 + i) * R + r0 + tx] = (bf16)tile[tx][ty * 4 + i];
}

// batched 1024x1024 convt: blockIdx.z selects matrix (saves 3 launch gaps)
__global__ void convt4(const float* __restrict__ s0, const float* __restrict__ s1,
                       const float* __restrict__ s2, const float* __restrict__ s3,
                       bf16* __restrict__ d0, bf16* __restrict__ d1,
                       bf16* __restrict__ d2, bf16* __restrict__ d3) {
  __shared__ float tile[32][33];
  const int z = blockIdx.z;                 // wave-uniform -> s_cselect
  const float* src = z == 0 ? s0 : z == 1 ? s1 : z == 2 ? s2 : s3;
  bf16* dst = z == 0 ? d0 : z == 1 ? d1 : z == 2 ? d2 : d3;
  int c0 = blockIdx.x * 32, r0 = blockIdx.y * 32;
  int tx = threadIdx.x, ty = threadIdx.y;
#pragma unroll
  for (int i = 0; i < 4; ++i)
    tile[ty * 4 + i][tx] = src[(size_t)(r0 + ty * 4 + i) * 1024 + c0 + tx];
  __syncthreads();
#pragma unroll
  for (int i = 0; i < 4; ++i)
    dst[(size_t)(c0 + ty * 4 + i) * 1024 + r0 + tx] = (bf16)tile[tx][ty * 4 + i];
}

// ---------------------------------------------------------------- 2-phase BM=256 GEMM (R14 proven)
// C[M][N] = A[M][K] @ BT[N][K]^T + bias (+res) (+gelu); output bf16.
// BM=256, BN=256, BK=64. 512 threads, 8 waves (2Mx4N), wave tile 128x64.
// Merged 2-phase schedule (3 barriers/tile, ~21 MFMA/barrier):
//   read aLo(8)+bF0(4)+bF1(4); barrier; MFMA m-lo x n0-3 (32);
//   read aHi(8); lgkmcnt(0); barrier;       <- aHi consumed AFTER barrier
//   stage A+B(t+2) into buf t&1; MFMA m-hi x n0-3 (32); vmcnt(8); barrier.
// vmcnt(8) completes t+1's 8 loads, leaves t+2's in flight (T4).
// 0-conflict XOR swizzle (chunk^=row&7).
template <int RES, int GELU, int SPLIT3>   // RES: 0 none, 1 fp32, 2 bf16
__global__ __launch_bounds__(512) void gemm_f(
    const bf16* __restrict__ A, const bf16* __restrict__ BT,
    const float* __restrict__ bias, const float* __restrict__ bias2,
    const float* __restrict__ bias3, const float* __restrict__ resf,
    const bf16* __restrict__ resb, bf16* __restrict__ C,
    bf16* __restrict__ C2, bf16* __restrict__ C3,
    int M, int N, int K) {
  __shared__ alignas(16) bf16 sA[2][256 * 64];
  __shared__ alignas(16) bf16 sB[2][256 * 64];

  const int tid = threadIdx.x;
  const int lane = tid & 63, wv = tid >> 6;
  const int wr = wv >> 2, wc = wv & 3;       // 2 x 4 wave grid
  const int r16 = lane & 15, hk = lane >> 4;

  const int nbn = N >> 8;
  const int cpx = gridDim.x >> 3;            // grid % 8 == 0
  const int swz = ((int)blockIdx.x & 7) * cpx + ((int)blockIdx.x >> 3);
  const int row0 = (swz / nbn) << 8, col0 = (swz % nbn) << 8;

  const bf16* Ab = A + (size_t)row0 * K;
  const bf16* Bb = BT + (size_t)col0 * K;

  const bf16* gA[4];
  const bf16* gB[4];
#pragma unroll
  for (int l = 0; l < 4; ++l) {
    int g = l * 512 + tid, r = g >> 3, p = g & 7;
    gA[l] = Ab + (size_t)r * K + ((p ^ (r & 7)) << 3);
    gB[l] = Bb + (size_t)r * K + ((p ^ (r & 7)) << 3);
  }

  auto stage = [&](int buf, int kt) {
    const size_t ko = (size_t)kt << 6;
#pragma unroll
    for (int l = 0; l < 4; ++l)
      gload_lds16(gA[l] + ko, &sA[buf][(l * 512 + tid) * 8]);
#pragma unroll
    for (int l = 0; l < 4; ++l)
      gload_lds16(gB[l] + ko, &sB[buf][(l * 512 + tid) * 8]);
  };
  auto frag = [&](const bf16* s, int row, int kc) -> bf16x8 {
    return *(const bf16x8*)(s + row * 64 + (kc ^ ((row & 7) * 8)));
  };

  f32x4 acc[8][4] = {};
  bf16x8 aF[4][2], bF0[2][2], bF1[2][2];

  const int nt = K >> 6;
  stage(0, 0);
  stage(1, 1);
  asm volatile("s_waitcnt vmcnt(8)" ::: "memory");   // tile 0 done, tile 1 in flight
  __builtin_amdgcn_s_barrier();

  for (int kt = 0; kt < nt; ++kt) {
    const int cb = kt & 1;
    const bf16* sa = &sA[cb][0];
    const bf16* sb = &sB[cb][0];
    const bool pf = (kt + 2 < nt);

    // ---- top reads: aLo + all B ----
#pragma unroll
    for (int m = 0; m < 4; ++m)
#pragma unroll
      for (int ks = 0; ks < 2; ++ks)
        aF[m][ks] = frag(sa, wr * 128 + m * 16 + r16, ks * 32 + hk * 8);
#pragma unroll
    for (int n = 0; n < 2; ++n)
#pragma unroll
      for (int ks = 0; ks < 2; ++ks) {
        bF0[n][ks] = frag(sb, wc * 64 + n * 16 + r16, ks * 32 + hk * 8);
        bF1[n][ks] = frag(sb, wc * 64 + (2 + n) * 16 + r16, ks * 32 + hk * 8);
      }
    __builtin_amdgcn_s_barrier();

    // ---- MFMA m-lo x n0-3 (32) ----
    __builtin_amdgcn_s_setprio(1);
#pragma unroll
    for (int ks = 0; ks < 2; ++ks)
#pragma unroll
      for (int m = 0; m < 4; ++m)
#pragma unroll
        for (int n = 0; n < 2; ++n) {
          acc[m][n]     = __builtin_amdgcn_mfma_f32_16x16x32_bf16(bF0[n][ks], aF[m][ks], acc[m][n], 0, 0, 0);
          acc[m][2 + n] = __builtin_amdgcn_mfma_f32_16x16x32_bf16(bF1[n][ks], aF[m][ks], acc[m][2 + n], 0, 0, 0);
        }
    __builtin_amdgcn_s_setprio(0);

    // ---- read aHi (reuse aF); must COMPLETE before next barrier ----
#pragma unroll
    for (int m = 0; m < 4; ++m)
#pragma unroll
      for (int ks = 0; ks < 2; ++ks)
        aF[m][ks] = frag(sa, wr * 128 + (4 + m) * 16 + r16, ks * 32 + hk * 8);
    asm volatile("s_waitcnt lgkmcnt(0)" ::: "memory");
    __builtin_amdgcn_s_barrier();

    // ---- stage t+2 into cb (all reads of cb complete & published) ----
    if (pf) stage(cb, kt + 2);

    // ---- MFMA m-hi x n0-3 (32) ----
    __builtin_amdgcn_s_setprio(1);
#pragma unroll
    for (int ks = 0; ks < 2; ++ks)
#pragma unroll
      for (int m = 0; m < 4; ++m)
#pragma unroll
        for (int n = 0; n < 2; ++n) {
          acc[4 + m][n]     = __builtin_amdgcn_mfma_f32_16x16x32_bf16(bF0[n][ks], aF[m][ks], acc[4 + m][n], 0, 0, 0);
          acc[4 + m][2 + n] = __builtin_amdgcn_mfma_f32_16x16x32_bf16(bF1[n][ks], aF[m][ks], acc[4 + m][2 + n], 0, 0, 0);
        }
    __builtin_amdgcn_s_setprio(0);
    if (pf) {
      asm volatile("s_waitcnt vmcnt(8)" ::: "memory");  // t+1 done; t+2 in flight
    } else if (kt + 1 < nt) {
      asm volatile("s_waitcnt vmcnt(0)" ::: "memory");
    }
    __builtin_amdgcn_s_barrier();
  }

  // ---- epilogue ----
  bf16* Cp = C;
  const float* bp = bias;
  int ldc = N, colb = col0;
  if constexpr (SPLIT3) {
    int grp = col0 >> 10;
    Cp = grp == 0 ? C : (grp == 1 ? C2 : C3);
    bp = grp == 0 ? bias : (grp == 1 ? bias2 : bias3);
    ldc = 1024;
    colb = col0 & 1023;
  }
#pragma unroll
  for (int m = 0; m < 8; ++m) {
    int row = row0 + wr * 128 + m * 16 + r16;
#pragma unroll
    for (int n = 0; n < 4; ++n) {
      int col = colb + wc * 64 + n * 16 + hk * 4;
      f32x4 b4 = *(const f32x4*)&bp[col];
      f32x4 v;
#pragma unroll
      for (int r = 0; r < 4; ++r) v[r] = acc[m][n][r] + b4[r];
      if (RES == 1) {
        f32x4 rr = *(const f32x4*)&resf[(size_t)row * ldc + col];
#pragma unroll
        for (int r = 0; r < 4; ++r) v[r] += rr[r];
      }
      if (RES == 2) {
        bf16x4 rb = *(const bf16x4*)&resb[(size_t)row * ldc + col];
#pragma unroll
        for (int r = 0; r < 4; ++r) v[r] += (float)rb[r];
      }
      bf16x4 o;
#pragma unroll
      for (int r = 0; r < 4; ++r) {
        float x = v[r];
        if (GELU) x = gelu_fast(x);
        o[r] = (bf16)x;
      }
      *(bf16x4*)&Cp[(size_t)row * ldc + col] = o;
    }
  }
}

// ---------------------------------------------------------------- 2-phase BM=128 GEMM (deep-K / small-B)
// BM=128, BN=256, BK=64; 3 LDS buffers (144 KiB); vmcnt(6)/tile completes
// t+1, leaves t+2 in flight. RES: 1 fp32 residual (Wo), 2 bf16 (FFN-down).
template <int RES>
__global__ __launch_bounds__(512) void gemm_d(
    const bf16* __restrict__ A, const bf16* __restrict__ BT,
    const float* __restrict__ bias, const float* __restrict__ resf,
    const bf16* __restrict__ resb, bf16* __restrict__ C,
    int M, int N, int K) {
  __shared__ alignas(16) bf16 sA[3][128 * 64];   // 48 KiB
  __shared__ alignas(16) bf16 sB[3][256 * 64];   // 96 KiB

  const int tid = threadIdx.x;
  const int lane = tid & 63, wv = tid >> 6;
  const int wr = wv >> 2, wc = wv & 3;
  const int r16 = lane & 15, hk = lane >> 4;

  const int nbn = N >> 8;
  const int cpx = gridDim.x >> 3;
  const int swz = ((int)blockIdx.x & 7) * cpx + ((int)blockIdx.x >> 3);
  const int row0 = (swz / nbn) * 128, col0 = (swz % nbn) << 8;

  const bf16* Ab = A + (size_t)row0 * K;
  const bf16* Bb = BT + (size_t)col0 * K;

  const bf16* gA[2];
  const bf16* gB[4];
#pragma unroll
  for (int l = 0; l < 2; ++l) {
    int g = l * 512 + tid, r = g >> 3, p = g & 7;
    gA[l] = Ab + (size_t)r * K + ((p ^ (r & 7)) << 3);
  }
#pragma unroll
  for (int l = 0; l < 4; ++l) {
    int g = l * 512 + tid, r = g >> 3, p = g & 7;
    gB[l] = Bb + (size_t)r * K + ((p ^ (r & 7)) << 3);
  }

  auto stage = [&](int buf, int kt) {
    const size_t ko = (size_t)kt << 6;
#pragma unroll
    for (int l = 0; l < 2; ++l)
      gload_lds16(gA[l] + ko, &sA[buf][(l * 512 + tid) * 8]);
#pragma unroll
    for (int l = 0; l < 4; ++l)
      gload_lds16(gB[l] + ko, &sB[buf][(l * 512 + tid) * 8]);
  };
  auto frag = [&](const bf16* s, int row, int kc) -> bf16x8 {
    return *(const bf16x8*)(s + row * 64 + (kc ^ ((row & 7) * 8)));
  };

  f32x4 acc[4][4] = {};
  bf16x8 aF[4][2], bF0[2][2], bF1[2][2];

  const int nt = K >> 6;
  stage(0, 0);
  stage(1, 1);
  asm volatile("s_waitcnt vmcnt(6)" ::: "memory");
  __builtin_amdgcn_s_barrier();

  int cur = 0;
  for (int kt = 0; kt < nt; ++kt) {
    const bf16* sa = &sA[cur][0];
    const bf16* sb = &sB[cur][0];
    const int nx2 = (cur + 2 >= 3) ? cur - 1 : cur + 2;   // (kt+2)%3
    const bool pf = (kt + 2 < nt);

#pragma unroll
    for (int m = 0; m < 4; ++m)
#pragma unroll
      for (int ks = 0; ks < 2; ++ks)
        aF[m][ks] = frag(sa, wr * 64 + m * 16 + r16, ks * 32 + hk * 8);
#pragma unroll
    for (int n = 0; n < 2; ++n)
#pragma unroll
      for (int ks = 0; ks < 2; ++ks)
        bF0[n][ks] = frag(sb, wc * 64 + n * 16 + r16, ks * 32 + hk * 8);
    __builtin_amdgcn_s_barrier();
    __builtin_amdgcn_s_setprio(1);
#pragma unroll
    for (int ks = 0; ks < 2; ++ks)
#pragma unroll
      for (int m = 0; m < 4; ++m)
#pragma unroll
        for (int n = 0; n < 2; ++n)
          acc[m][n] = __builtin_amdgcn_mfma_f32_16x16x32_bf16(bF0[n][ks], aF[m][ks], acc[m][n], 0, 0, 0);
    __builtin_amdgcn_s_setprio(0);
    __builtin_amdgcn_s_barrier();

#pragma unroll
    for (int n = 0; n < 2; ++n)
#pragma unroll
      for (int ks = 0; ks < 2; ++ks)
        bF1[n][ks] = frag(sb, wc * 64 + (2 + n) * 16 + r16, ks * 32 + hk * 8);
    if (pf) stage(nx2, kt + 2);
    __builtin_amdgcn_s_barrier();
    __builtin_amdgcn_s_setprio(1);
#pragma unroll
    for (int ks = 0; ks < 2; ++ks)
#pragma unroll
      for (int m = 0; m < 4; ++m)
#pragma unroll
        for (int n = 0; n < 2; ++n)
          acc[m][2 + n] = __builtin_amdgcn_mfma_f32_16x16x32_bf16(bF1[n][ks], aF[m][ks], acc[m][2 + n], 0, 0, 0);
    __builtin_amdgcn_s_setprio(0);
    if (pf) {
      asm volatile("s_waitcnt vmcnt(6)" ::: "memory");
    } else if (kt + 1 < nt) {
      asm volatile("s_waitcnt vmcnt(0)" ::: "memory");
    }
    __builtin_amdgcn_s_barrier();
    cur = (cur + 1 == 3) ? 0 : cur + 1;
  }

#pragma unroll
  for (int m = 0; m < 4; ++m) {
    int row = row0 + wr * 64 + m * 16 + r16;
#pragma unroll
    for (int n = 0; n < 4; ++n) {
      int col = col0 + wc * 64 + n * 16 + hk * 4;
      f32x4 b4 = *(const f32x4*)&bias[col];
      f32x4 v;
#pragma unroll
      for (int r = 0; r < 4; ++r) v[r] = acc[m][n][r] + b4[r];
      if (RES == 1) {
        f32x4 rr = *(const f32x4*)&resf[(size_t)row * N + col];
#pragma unroll
        for (int r = 0; r < 4; ++r) v[r] += rr[r];
      }
      if (RES == 2) {
        bf16x4 rb = *(const bf16x4*)&resb[(size_t)row * N + col];
#pragma unroll
        for (int r = 0; r < 4; ++r) v[r] += (float)rb[r];
      }
      bf16x4 o;
#pragma unroll
      for (int r = 0; r < 4; ++r) o[r] = (bf16)v[r];
      *(bf16x4*)&C[(size_t)row * N + col] = o;
    }
  }
}

// ---------------------------------------------------------------- attention
// one block per (b,h); L=64, dh=64. ctx may alias q.
__global__ __launch_bounds__(256) void attn_k(
    const bf16* q, const bf16* __restrict__ k,
    const bf16* __restrict__ v, const float* __restrict__ rel,
    bf16* ctx) {
  __shared__ alignas(16) bf16 lQ[64 * 64];
  __shared__ alignas(16) bf16 lK[64 * 64];
  __shared__ alignas(16) bf16 lVt[64 * 64];
  __shared__ alignas(16) bf16 lP[4][16 * 64];
  __shared__ float lrel[128];

  const int bh = blockIdx.x;
  const int b = bh >> 4, h = bh & 15;
  const int tid = threadIdx.x;
  const size_t base = (size_t)(b * 64) * DMODEL + h * 64;

#pragma unroll
  for (int i = 0; i < 2; ++i) {
    int j = (tid >> 3) + i * 32;
    int d0 = (tid & 7) * 8;
    *(bf16x8*)&lQ[j * 64 + d0] = *(const bf16x8*)(q + base + (size_t)j * DMODEL + d0);
    *(bf16x8*)&lK[j * 64 + d0] = *(const bf16x8*)(k + base + (size_t)j * DMODEL + d0);
    bf16x8 vvv = *(const bf16x8*)(v + base + (size_t)j * DMODEL + d0);
#pragma unroll
    for (int u = 0; u < 8; ++u) lVt[(d0 + u) * 64 + j] = vvv[u];
  }
  if (tid < 127) lrel[tid] = rel[h * 127 + tid];
  __syncthreads();

  const int lane = tid & 63, w = tid >> 6;
  const int r16 = lane & 15, hk = lane >> 4;

  f32x4 s[4] = {};
#pragma unroll
  for (int dstep = 0; dstep < 2; ++dstep) {
    bf16x8 aq = *(const bf16x8*)&lQ[(w * 16 + r16) * 64 + dstep * 32 + hk * 8];
#pragma unroll
    for (int n = 0; n < 4; ++n) {
      bf16x8 bk_ = *(const bf16x8*)&lK[(n * 16 + r16) * 64 + dstep * 32 + hk * 8];
      s[n] = __builtin_amdgcn_mfma_f32_16x16x32_bf16(aq, bk_, s[n], 0, 0, 0);
    }
  }

  float p[16];
#pragma unroll
  for (int n = 0; n < 4; ++n)
#pragma unroll
    for (int r = 0; r < 4; ++r) {
      int i = w * 16 + hk * 4 + r;
      int j = n * 16 + r16;
      p[n * 4 + r] = s[n][r] * 0.125f + lrel[i - j + 63];
    }
#pragma unroll
  for (int r = 0; r < 4; ++r) {
    float m = fmaxf(fmaxf(p[r], p[4 + r]), fmaxf(p[8 + r], p[12 + r]));
#pragma unroll
    for (int off = 1; off < 16; off <<= 1) m = fmaxf(m, __shfl_xor(m, off));
    float sum = 0.f;
#pragma unroll
    for (int n = 0; n < 4; ++n) {
      p[n * 4 + r] = __expf(p[n * 4 + r] - m);
      sum += p[n * 4 + r];
    }
#pragma unroll
    for (int off = 1; off < 16; off <<= 1) sum += __shfl_xor(sum, off);
    float inv = 1.0f / sum;
#pragma unroll
    for (int n = 0; n < 4; ++n) p[n * 4 + r] *= inv;
  }
#pragma unroll
  for (int n = 0; n < 4; ++n)
#pragma unroll
    for (int r = 0; r < 4; ++r)
      lP[w][(hk * 4 + r) * 64 + n * 16 + r16] = (bf16)p[n * 4 + r];
  __syncthreads();

  f32x4 o[4] = {};
#pragma unroll
  for (int ks = 0; ks < 2; ++ks) {
    bf16x8 ap = *(const bf16x8*)&lP[w][r16 * 64 + ks * 32 + hk * 8];
#pragma unroll
    for (int n = 0; n < 4; ++n) {
      bf16x8 bv_ = *(const bf16x8*)&lVt[(n * 16 + r16) * 64 + ks * 32 + hk * 8];
      o[n] = __builtin_amdgcn_mfma_f32_16x16x32_bf16(ap, bv_, o[n], 0, 0, 0);
    }
  }
#pragma unroll
  for (int n = 0; n < 4; ++n)
#pragma unroll
    for (int r = 0; r < 4; ++r) {
      int trow = b * 64 + w * 16 + hk * 4 + r;
      ctx[(size_t)trow * DMODEL + h * 64 + n * 16 + r16] = (bf16)o[n][r];
    }
}

// ---------------------------------------------------------------- layernorm
template <int F32OUT>
__global__ __launch_bounds__(256) void layernorm_k(
    const bf16* __restrict__ x, const float* __restrict__ g,
    const float* __restrict__ be, bf16* __restrict__ ob,
    float* __restrict__ of) {
  int row = blockIdx.x * 4 + (threadIdx.x >> 6);
  int lane = threadIdx.x & 63;
  const bf16* xr = x + (size_t)row * DMODEL + lane * 16;
  bf16x8 v0 = *(const bf16x8*)xr;
  bf16x8 v1 = *(const bf16x8*)(xr + 8);
  float f[16];
#pragma unroll
  for (int j = 0; j < 8; ++j) { f[j] = (float)v0[j]; f[8 + j] = (float)v1[j]; }
  float s = 0.f, sq = 0.f;
#pragma unroll
  for (int j = 0; j < 16; ++j) { s += f[j]; sq += f[j] * f[j]; }
#pragma unroll
  for (int off = 1; off < 64; off <<= 1) {
    s += __shfl_xor(s, off);
    sq += __shfl_xor(sq, off);
  }
  float mean = s * (1.0f / DMODEL);
  float var = sq * (1.0f / DMODEL) - mean * mean;
  float rstd = rsqrtf(var + 1e-5f);
  const float* gp = g + lane * 16;
  const float* bp = be + lane * 16;
  if (F32OUT) {
    float* op = of + (size_t)row * DMODEL + lane * 16;
#pragma unroll
    for (int j = 0; j < 16; ++j)
      op[j] = (f[j] - mean) * rstd * gp[j] + bp[j];
  } else {
    bf16x8 o0, o1;
#pragma unroll
    for (int j = 0; j < 8; ++j) {
      o0[j] = (bf16)((f[j] - mean) * rstd * gp[j] + bp[j]);
      o1[j] = (bf16)((f[8 + j] - mean) * rstd * gp[8 + j] + bp[8 + j]);
    }
    bf16* op = ob + (size_t)row * DMODEL + lane * 16;
    *(bf16x8*)op = o0;
    *(bf16x8*)(op + 8) = o1;
  }
}

// ---------------------------------------------------------------- launch
extern "C" void kernel_launch(void* const* d_in, const int* in_sizes, int n_in,
                              void* d_out, int out_size, void* d_ws, size_t ws_size,
                              hipStream_t stream) {
  (void)in_sizes; (void)n_in; (void)out_size;
  const float* src = (const float*)d_in[0];
  const float* Wq  = (const float*)d_in[1];
  const float* bq  = (const float*)d_in[2];
  const float* Wk  = (const float*)d_in[3];
  const float* bk  = (const float*)d_in[4];
  const float* Wv  = (const float*)d_in[5];
  const float* bv  = (const float*)d_in[6];
  const float* Wo  = (const float*)d_in[7];
  const float* bo  = (const float*)d_in[8];
  const float* rel = (const float*)d_in[9];
  const float* W1  = (const float*)d_in[10];
  const float* b1  = (const float*)d_in[11];
  const float* W2  = (const float*)d_in[12];
  const float* b2  = (const float*)d_in[13];
  const float* g1  = (const float*)d_in[14];
  const float* be1 = (const float*)d_in[15];
  const float* g2  = (const float*)d_in[16];
  const float* be2 = (const float*)d_in[17];

  // ws plan: REGION0 = ws[0:64MiB] (srcb+qb -> hbuf -> lnout);
  // weights ws[64:88MiB] (WqT/WkT/WvT contiguous => fused QKV B matrix);
  // y2 in ws[88:120MiB] when ws_size allows, else d_out + copy-out.
  char* ws = (char*)d_ws;
  const size_t MiB = 1ull << 20;
  bf16* srcb = (bf16*)(ws + 0 * MiB);
  bf16* qb   = (bf16*)(ws + 32 * MiB);
  bf16* WqT  = (bf16*)(ws + 64 * MiB);   // [3072][1024] fused: Wq|Wk|Wv
  bf16* WkT  = (bf16*)(ws + 66 * MiB);
  bf16* WvT  = (bf16*)(ws + 68 * MiB);
  bf16* WoT  = (bf16*)(ws + 70 * MiB);
  bf16* W1T  = (bf16*)(ws + 72 * MiB);
  bf16* W2T  = (bf16*)(ws + 80 * MiB);
  bf16* hbuf = (bf16*)(ws + 0 * MiB);
  float* lnout = (float*)(ws + 0 * MiB);
  bf16* kb = (bf16*)d_out;
  bf16* vb = (bf16*)((char*)d_out + 32 * MiB);
  bf16* y1 = kb;
  bf16* xb = vb;
  const bool bigws = (ws_size >= 121 * MiB);
  bf16* y2 = bigws ? (bf16*)(ws + 88 * MiB) : kb;

  cvt_copy<<<(N_TOK * DMODEL) / 2048, 256, 0, stream>>>(src, srcb);
  dim3 tb(32, 8);
  convt4<<<dim3(32, 32, 4), tb, 0, stream>>>(Wq, Wk, Wv, Wo, WqT, WkT, WvT, WoT);
  convt<<<dim3(128, 32), tb, 0, stream>>>(W1, W1T, 1024, 4096);
  convt<<<dim3(32, 128), tb, 0, stream>>>(W2, W2T, 4096, 1024);

  // fused QKV: one GEMM, N=3072 (WqT/WkT/WvT contiguous), split outputs
  const int gQKV3 = (N_TOK / 256) * (3072 / 256);   // 64*12 = 768
  gemm_f<0, 0, 1><<<gQKV3, 512, 0, stream>>>(
      srcb, WqT, bq, bk, bv, nullptr, nullptr, qb, kb, vb, N_TOK, 3072, DMODEL);

  attn_k<<<256 * NHEAD, 256, 0, stream>>>(qb, kb, vb, rel, qb);

  // y1 = ctx @ Wo + bo + src (fp32 residual); Wo B-panel (2 MiB) is
  // L2-resident so BM=128 gemm_d has no re-fetch penalty.
  const int gWo = (N_TOK / 128) * (DMODEL / 256);   // 128*4 = 512
  gemm_d<1><<<gWo, 512, 0, stream>>>(qb, WoT, bo, src, nullptr, y1, N_TOK, DMODEL, DMODEL);
  // x = LN1(y1) -> DO1
  layernorm_k<0><<<N_TOK / 4, 256, 0, stream>>>(y1, g1, be1, xb, nullptr);

  // FFN in 2 chunks of 8192 rows; h (8192x4096 bf16 = 64 MiB) in REGION0
  const int CH = 8192;
  const int gF1 = (CH / 256) * (FDIM / 256);     // 32*16 = 512
  const int gF2 = (CH / 128) * (DMODEL / 256);   // 64*4  = 256
  for (int c = 0; c < 2; ++c) {
    const bf16* xc = xb + (size_t)c * CH * DMODEL;
    bf16* yc = y2 + (size_t)c * CH * DMODEL;
    gemm_f<0, 1, 0><<<gF1, 512, 0, stream>>>(
        xc, W1T, b1, nullptr, nullptr, nullptr, nullptr, hbuf, nullptr, nullptr, CH, FDIM, DMODEL);
    gemm_d<2><<<gF2, 512, 0, stream>>>(hbuf, W2T, b2, nullptr, xc, yc, CH, DMODEL, FDIM);
  }
  if (bigws) {
    layernorm_k<1><<<N_TOK / 4, 256, 0, stream>>>(y2, g2, be2, nullptr, (float*)d_out);
  } else {
    layernorm_k<1><<<N_TOK / 4, 256, 0, stream>>>(y2, g2, be2, nullptr, lnout);
    hipMemcpyAsync(d_out, lnout, (size_t)N_TOK * DMODEL * 4, hipMemcpyDeviceToDevice, stream);
  }
}

// Round 17
// 596.600 us; speedup vs baseline: 1.0170x; 1.0009x over previous
//
#include <hip/hip_runtime.h>

typedef __bf16 bf16;
typedef __attribute__((ext_vector_type(8))) __bf16 bf16x8;
typedef __attribute__((ext_vector_type(4))) __bf16 bf16x4;
typedef __attribute__((ext_vector_type(4))) float f32x4;

#define N_TOK 16384
#define DMODEL 1024
#define FDIM 4096
#define NHEAD 16

// ---------------------------------------------------------------- helpers
__device__ __forceinline__ void gload_lds16(const bf16* g, bf16* l) {
  __builtin_amdgcn_global_load_lds(
      (const __attribute__((address_space(1))) void*)g,
      (__attribute__((address_space(3))) void*)l,
      16, 0, 0);
}

// gelu(x) = 0.5x(1+tanh(z)) = x / (1 + exp(-2z)),  z = 0.79788456(x + 0.044715x^3)
__device__ __forceinline__ float gelu_fast(float x) {
  float z2 = 1.5957691216057308f * (x + 0.044715f * x * x * x);
  return x / (1.0f + __expf(-z2));
}

// ---------------------------------------------------------------- fp32 -> bf16 copy
__global__ __launch_bounds__(256) void cvt_copy(const float* __restrict__ x,
                                                bf16* __restrict__ y) {
  size_t i = ((size_t)blockIdx.x * 256 + threadIdx.x) * 8;
  float4 a = *(const float4*)(x + i);
  float4 b = *(const float4*)(x + i + 4);
  bf16x8 o;
  o[0] = (bf16)a.x; o[1] = (bf16)a.y; o[2] = (bf16)a.z; o[3] = (bf16)a.w;
  o[4] = (bf16)b.x; o[5] = (bf16)b.y; o[6] = (bf16)b.z; o[7] = (bf16)b.w;
  *(bf16x8*)(y + i) = o;
}

// ---------------------------------------------------------------- convert+transpose
__global__ void convt(const float* __restrict__ src, bf16* __restrict__ dst,
                      int R, int C) {
  __shared__ float tile[32][33];
  int c0 = blockIdx.x * 32, r0 = blockIdx.y * 32;
  int tx = threadIdx.x, ty = threadIdx.y;
#pragma unroll
  for (int i = 0; i < 4; ++i)
    tile[ty * 4 + i][tx] = src[(size_t)(r0 + ty * 4 + i) * C + c0 + tx];
  __syncthreads();
#pragma unroll
  for (int i = 0; i < 4; ++i)
    dst[(size_t)(c0 + ty * 4 + i) * R + r0 + tx] = (bf16)tile[tx][ty * 4 + i];
}

// batched 1024x1024 convt: blockIdx.z selects matrix (saves 3 launch gaps)
__global__ void convt4(const float* __restrict__ s0, const float* __restrict__ s1,
                       const float* __restrict__ s2, const float* __restrict__ s3,
                       bf16* __restrict__ d0, bf16* __restrict__ d1,
                       bf16* __restrict__ d2, bf16* __restrict__ d3) {
  __shared__ float tile[32][33];
  const int z = blockIdx.z;                 // wave-uniform -> s_cselect
  const float* src = z == 0 ? s0 : z == 1 ? s1 : z == 2 ? s2 : s3;
  bf16* dst = z == 0 ? d0 : z == 1 ? d1 : z == 2 ? d2 : d3;
  int c0 = blockIdx.x * 32, r0 = blockIdx.y * 32;
  int tx = threadIdx.x, ty = threadIdx.y;
#pragma unroll
  for (int i = 0; i < 4; ++i)
    tile[ty * 4 + i][tx] = src[(size_t)(r0 + ty * 4 + i) * 1024 + c0 + tx];
  __syncthreads();
#pragma unroll
  for (int i = 0; i < 4; ++i)
    dst[(size_t)(c0 + ty * 4 + i) * 1024 + r0 + tx] = (bf16)tile[tx][ty * 4 + i];
}

// ---------------------------------------------------------------- 2-phase BM=256 GEMM (session best)
// C[M][N] = A[M][K] @ BT[N][K]^T + bias (+res) (+gelu); output bf16.
// BM=256, BN=256, BK=64. 512 threads, 8 waves (2Mx4N), wave tile 128x64.
// Merged 2-phase schedule (3 barriers/tile, ~21 MFMA/barrier):
//   read aLo(8)+bF0(4)+bF1(4); barrier; MFMA m-lo x n0-3 (32);
//   read aHi(8); lgkmcnt(0); barrier;       <- aHi consumed AFTER barrier
//   stage A+B(t+2) into buf t&1; MFMA m-hi x n0-3 (32); vmcnt(8); barrier.
// vmcnt(8) completes t+1's 8 loads, leaves t+2's in flight (T4).
// 0-conflict XOR swizzle (chunk^=row&7).
template <int RES, int GELU, int SPLIT3>   // RES: 0 none, 1 fp32, 2 bf16
__global__ __launch_bounds__(512) void gemm_f(
    const bf16* __restrict__ A, const bf16* __restrict__ BT,
    const float* __restrict__ bias, const float* __restrict__ bias2,
    const float* __restrict__ bias3, const float* __restrict__ resf,
    const bf16* __restrict__ resb, bf16* __restrict__ C,
    bf16* __restrict__ C2, bf16* __restrict__ C3,
    int M, int N, int K) {
  __shared__ alignas(16) bf16 sA[2][256 * 64];
  __shared__ alignas(16) bf16 sB[2][256 * 64];

  const int tid = threadIdx.x;
  const int lane = tid & 63, wv = tid >> 6;
  const int wr = wv >> 2, wc = wv & 3;       // 2 x 4 wave grid
  const int r16 = lane & 15, hk = lane >> 4;

  const int nbn = N >> 8;
  const int cpx = gridDim.x >> 3;            // grid % 8 == 0
  const int swz = ((int)blockIdx.x & 7) * cpx + ((int)blockIdx.x >> 3);
  const int row0 = (swz / nbn) << 8, col0 = (swz % nbn) << 8;

  const bf16* Ab = A + (size_t)row0 * K;
  const bf16* Bb = BT + (size_t)col0 * K;

  const bf16* gA[4];
  const bf16* gB[4];
#pragma unroll
  for (int l = 0; l < 4; ++l) {
    int g = l * 512 + tid, r = g >> 3, p = g & 7;
    gA[l] = Ab + (size_t)r * K + ((p ^ (r & 7)) << 3);
    gB[l] = Bb + (size_t)r * K + ((p ^ (r & 7)) << 3);
  }

  auto stage = [&](int buf, int kt) {
    const size_t ko = (size_t)kt << 6;
#pragma unroll
    for (int l = 0; l < 4; ++l)
      gload_lds16(gA[l] + ko, &sA[buf][(l * 512 + tid) * 8]);
#pragma unroll
    for (int l = 0; l < 4; ++l)
      gload_lds16(gB[l] + ko, &sB[buf][(l * 512 + tid) * 8]);
  };
  auto frag = [&](const bf16* s, int row, int kc) -> bf16x8 {
    return *(const bf16x8*)(s + row * 64 + (kc ^ ((row & 7) * 8)));
  };

  f32x4 acc[8][4] = {};
  bf16x8 aF[4][2], bF0[2][2], bF1[2][2];

  const int nt = K >> 6;
  stage(0, 0);
  stage(1, 1);
  asm volatile("s_waitcnt vmcnt(8)" ::: "memory");   // tile 0 done, tile 1 in flight
  __builtin_amdgcn_s_barrier();

  for (int kt = 0; kt < nt; ++kt) {
    const int cb = kt & 1;
    const bf16* sa = &sA[cb][0];
    const bf16* sb = &sB[cb][0];
    const bool pf = (kt + 2 < nt);

    // ---- top reads: aLo + all B ----
#pragma unroll
    for (int m = 0; m < 4; ++m)
#pragma unroll
      for (int ks = 0; ks < 2; ++ks)
        aF[m][ks] = frag(sa, wr * 128 + m * 16 + r16, ks * 32 + hk * 8);
#pragma unroll
    for (int n = 0; n < 2; ++n)
#pragma unroll
      for (int ks = 0; ks < 2; ++ks) {
        bF0[n][ks] = frag(sb, wc * 64 + n * 16 + r16, ks * 32 + hk * 8);
        bF1[n][ks] = frag(sb, wc * 64 + (2 + n) * 16 + r16, ks * 32 + hk * 8);
      }
    __builtin_amdgcn_s_barrier();

    // ---- MFMA m-lo x n0-3 (32) ----
    __builtin_amdgcn_s_setprio(1);
#pragma unroll
    for (int ks = 0; ks < 2; ++ks)
#pragma unroll
      for (int m = 0; m < 4; ++m)
#pragma unroll
        for (int n = 0; n < 2; ++n) {
          acc[m][n]     = __builtin_amdgcn_mfma_f32_16x16x32_bf16(bF0[n][ks], aF[m][ks], acc[m][n], 0, 0, 0);
          acc[m][2 + n] = __builtin_amdgcn_mfma_f32_16x16x32_bf16(bF1[n][ks], aF[m][ks], acc[m][2 + n], 0, 0, 0);
        }
    __builtin_amdgcn_s_setprio(0);

    // ---- read aHi (reuse aF); must COMPLETE before next barrier ----
#pragma unroll
    for (int m = 0; m < 4; ++m)
#pragma unroll
      for (int ks = 0; ks < 2; ++ks)
        aF[m][ks] = frag(sa, wr * 128 + (4 + m) * 16 + r16, ks * 32 + hk * 8);
    asm volatile("s_waitcnt lgkmcnt(0)" ::: "memory");
    __builtin_amdgcn_s_barrier();

    // ---- stage t+2 into cb (all reads of cb complete & published) ----
    if (pf) stage(cb, kt + 2);

    // ---- MFMA m-hi x n0-3 (32) ----
    __builtin_amdgcn_s_setprio(1);
#pragma unroll
    for (int ks = 0; ks < 2; ++ks)
#pragma unroll
      for (int m = 0; m < 4; ++m)
#pragma unroll
        for (int n = 0; n < 2; ++n) {
          acc[4 + m][n]     = __builtin_amdgcn_mfma_f32_16x16x32_bf16(bF0[n][ks], aF[m][ks], acc[4 + m][n], 0, 0, 0);
          acc[4 + m][2 + n] = __builtin_amdgcn_mfma_f32_16x16x32_bf16(bF1[n][ks], aF[m][ks], acc[4 + m][2 + n], 0, 0, 0);
        }
    __builtin_amdgcn_s_setprio(0);
    if (pf) {
      asm volatile("s_waitcnt vmcnt(8)" ::: "memory");  // t+1 done; t+2 in flight
    } else if (kt + 1 < nt) {
      asm volatile("s_waitcnt vmcnt(0)" ::: "memory");
    }
    __builtin_amdgcn_s_barrier();
  }

  // ---- epilogue ----
  bf16* Cp = C;
  const float* bp = bias;
  int ldc = N, colb = col0;
  if constexpr (SPLIT3) {
    int grp = col0 >> 10;
    Cp = grp == 0 ? C : (grp == 1 ? C2 : C3);
    bp = grp == 0 ? bias : (grp == 1 ? bias2 : bias3);
    ldc = 1024;
    colb = col0 & 1023;
  }
#pragma unroll
  for (int m = 0; m < 8; ++m) {
    int row = row0 + wr * 128 + m * 16 + r16;
#pragma unroll
    for (int n = 0; n < 4; ++n) {
      int col = colb + wc * 64 + n * 16 + hk * 4;
      f32x4 b4 = *(const f32x4*)&bp[col];
      f32x4 v;
#pragma unroll
      for (int r = 0; r < 4; ++r) v[r] = acc[m][n][r] + b4[r];
      if (RES == 1) {
        f32x4 rr = *(const f32x4*)&resf[(size_t)row * ldc + col];
#pragma unroll
        for (int r = 0; r < 4; ++r) v[r] += rr[r];
      }
      if (RES == 2) {
        bf16x4 rb = *(const bf16x4*)&resb[(size_t)row * ldc + col];
#pragma unroll
        for (int r = 0; r < 4; ++r) v[r] += (float)rb[r];
      }
      bf16x4 o;
#pragma unroll
      for (int r = 0; r < 4; ++r) {
        float x = v[r];
        if (GELU) x = gelu_fast(x);
        o[r] = (bf16)x;
      }
      *(bf16x4*)&Cp[(size_t)row * ldc + col] = o;
    }
  }
}

// ---------------------------------------------------------------- 2-phase BM=128 GEMM (deep-K / small-B)
// BM=128, BN=256, BK=64; 3 LDS buffers (144 KiB); vmcnt(6)/tile completes
// t+1, leaves t+2 in flight. RES: 1 fp32 residual (Wo), 2 bf16 (FFN-down).
template <int RES>
__global__ __launch_bounds__(512) void gemm_d(
    const bf16* __restrict__ A, const bf16* __restrict__ BT,
    const float* __restrict__ bias, const float* __restrict__ resf,
    const bf16* __restrict__ resb, bf16* __restrict__ C,
    int M, int N, int K) {
  __shared__ alignas(16) bf16 sA[3][128 * 64];   // 48 KiB
  __shared__ alignas(16) bf16 sB[3][256 * 64];   // 96 KiB

  const int tid = threadIdx.x;
  const int lane = tid & 63, wv = tid >> 6;
  const int wr = wv >> 2, wc = wv & 3;
  const int r16 = lane & 15, hk = lane >> 4;

  const int nbn = N >> 8;
  const int cpx = gridDim.x >> 3;
  const int swz = ((int)blockIdx.x & 7) * cpx + ((int)blockIdx.x >> 3);
  const int row0 = (swz / nbn) * 128, col0 = (swz % nbn) << 8;

  const bf16* Ab = A + (size_t)row0 * K;
  const bf16* Bb = BT + (size_t)col0 * K;

  const bf16* gA[2];
  const bf16* gB[4];
#pragma unroll
  for (int l = 0; l < 2; ++l) {
    int g = l * 512 + tid, r = g >> 3, p = g & 7;
    gA[l] = Ab + (size_t)r * K + ((p ^ (r & 7)) << 3);
  }
#pragma unroll
  for (int l = 0; l < 4; ++l) {
    int g = l * 512 + tid, r = g >> 3, p = g & 7;
    gB[l] = Bb + (size_t)r * K + ((p ^ (r & 7)) << 3);
  }

  auto stage = [&](int buf, int kt) {
    const size_t ko = (size_t)kt << 6;
#pragma unroll
    for (int l = 0; l < 2; ++l)
      gload_lds16(gA[l] + ko, &sA[buf][(l * 512 + tid) * 8]);
#pragma unroll
    for (int l = 0; l < 4; ++l)
      gload_lds16(gB[l] + ko, &sB[buf][(l * 512 + tid) * 8]);
  };
  auto frag = [&](const bf16* s, int row, int kc) -> bf16x8 {
    return *(const bf16x8*)(s + row * 64 + (kc ^ ((row & 7) * 8)));
  };

  f32x4 acc[4][4] = {};
  bf16x8 aF[4][2], bF0[2][2], bF1[2][2];

  const int nt = K >> 6;
  stage(0, 0);
  stage(1, 1);
  asm volatile("s_waitcnt vmcnt(6)" ::: "memory");
  __builtin_amdgcn_s_barrier();

  int cur = 0;
  for (int kt = 0; kt < nt; ++kt) {
    const bf16* sa = &sA[cur][0];
    const bf16* sb = &sB[cur][0];
    const int nx2 = (cur + 2 >= 3) ? cur - 1 : cur + 2;   // (kt+2)%3
    const bool pf = (kt + 2 < nt);

#pragma unroll
    for (int m = 0; m < 4; ++m)
#pragma unroll
      for (int ks = 0; ks < 2; ++ks)
        aF[m][ks] = frag(sa, wr * 64 + m * 16 + r16, ks * 32 + hk * 8);
#pragma unroll
    for (int n = 0; n < 2; ++n)
#pragma unroll
      for (int ks = 0; ks < 2; ++ks)
        bF0[n][ks] = frag(sb, wc * 64 + n * 16 + r16, ks * 32 + hk * 8);
    __builtin_amdgcn_s_barrier();
    __builtin_amdgcn_s_setprio(1);
#pragma unroll
    for (int ks = 0; ks < 2; ++ks)
#pragma unroll
      for (int m = 0; m < 4; ++m)
#pragma unroll
        for (int n = 0; n < 2; ++n)
          acc[m][n] = __builtin_amdgcn_mfma_f32_16x16x32_bf16(bF0[n][ks], aF[m][ks], acc[m][n], 0, 0, 0);
    __builtin_amdgcn_s_setprio(0);
    __builtin_amdgcn_s_barrier();

#pragma unroll
    for (int n = 0; n < 2; ++n)
#pragma unroll
      for (int ks = 0; ks < 2; ++ks)
        bF1[n][ks] = frag(sb, wc * 64 + (2 + n) * 16 + r16, ks * 32 + hk * 8);
    if (pf) stage(nx2, kt + 2);
    __builtin_amdgcn_s_barrier();
    __builtin_amdgcn_s_setprio(1);
#pragma unroll
    for (int ks = 0; ks < 2; ++ks)
#pragma unroll
      for (int m = 0; m < 4; ++m)
#pragma unroll
        for (int n = 0; n < 2; ++n)
          acc[m][2 + n] = __builtin_amdgcn_mfma_f32_16x16x32_bf16(bF1[n][ks], aF[m][ks], acc[m][2 + n], 0, 0, 0);
    __builtin_amdgcn_s_setprio(0);
    if (pf) {
      asm volatile("s_waitcnt vmcnt(6)" ::: "memory");
    } else if (kt + 1 < nt) {
      asm volatile("s_waitcnt vmcnt(0)" ::: "memory");
    }
    __builtin_amdgcn_s_barrier();
    cur = (cur + 1 == 3) ? 0 : cur + 1;
  }

#pragma unroll
  for (int m = 0; m < 4; ++m) {
    int row = row0 + wr * 64 + m * 16 + r16;
#pragma unroll
    for (int n = 0; n < 4; ++n) {
      int col = col0 + wc * 64 + n * 16 + hk * 4;
      f32x4 b4 = *(const f32x4*)&bias[col];
      f32x4 v;
#pragma unroll
      for (int r = 0; r < 4; ++r) v[r] = acc[m][n][r] + b4[r];
      if (RES == 1) {
        f32x4 rr = *(const f32x4*)&resf[(size_t)row * N + col];
#pragma unroll
        for (int r = 0; r < 4; ++r) v[r] += rr[r];
      }
      if (RES == 2) {
        bf16x4 rb = *(const bf16x4*)&resb[(size_t)row * N + col];
#pragma unroll
        for (int r = 0; r < 4; ++r) v[r] += (float)rb[r];
      }
      bf16x4 o;
#pragma unroll
      for (int r = 0; r < 4; ++r) o[r] = (bf16)v[r];
      *(bf16x4*)&C[(size_t)row * N + col] = o;
    }
  }
}

// ---------------------------------------------------------------- attention
// one block per (b,h); L=64, dh=64. ctx may alias q.
__global__ __launch_bounds__(256) void attn_k(
    const bf16* q, const bf16* __restrict__ k,
    const bf16* __restrict__ v, const float* __restrict__ rel,
    bf16* ctx) {
  __shared__ alignas(16) bf16 lQ[64 * 64];
  __shared__ alignas(16) bf16 lK[64 * 64];
  __shared__ alignas(16) bf16 lVt[64 * 64];
  __shared__ alignas(16) bf16 lP[4][16 * 64];
  __shared__ float lrel[128];

  const int bh = blockIdx.x;
  const int b = bh >> 4, h = bh & 15;
  const int tid = threadIdx.x;
  const size_t base = (size_t)(b * 64) * DMODEL + h * 64;

#pragma unroll
  for (int i = 0; i < 2; ++i) {
    int j = (tid >> 3) + i * 32;
    int d0 = (tid & 7) * 8;
    *(bf16x8*)&lQ[j * 64 + d0] = *(const bf16x8*)(q + base + (size_t)j * DMODEL + d0);
    *(bf16x8*)&lK[j * 64 + d0] = *(const bf16x8*)(k + base + (size_t)j * DMODEL + d0);
    bf16x8 vvv = *(const bf16x8*)(v + base + (size_t)j * DMODEL + d0);
#pragma unroll
    for (int u = 0; u < 8; ++u) lVt[(d0 + u) * 64 + j] = vvv[u];
  }
  if (tid < 127) lrel[tid] = rel[h * 127 + tid];
  __syncthreads();

  const int lane = tid & 63, w = tid >> 6;
  const int r16 = lane & 15, hk = lane >> 4;

  f32x4 s[4] = {};
#pragma unroll
  for (int dstep = 0; dstep < 2; ++dstep) {
    bf16x8 aq = *(const bf16x8*)&lQ[(w * 16 + r16) * 64 + dstep * 32 + hk * 8];
#pragma unroll
    for (int n = 0; n < 4; ++n) {
      bf16x8 bk_ = *(const bf16x8*)&lK[(n * 16 + r16) * 64 + dstep * 32 + hk * 8];
      s[n] = __builtin_amdgcn_mfma_f32_16x16x32_bf16(aq, bk_, s[n], 0, 0, 0);
    }
  }

  float p[16];
#pragma unroll
  for (int n = 0; n < 4; ++n)
#pragma unroll
    for (int r = 0; r < 4; ++r) {
      int i = w * 16 + hk * 4 + r;
      int j = n * 16 + r16;
      p[n * 4 + r] = s[n][r] * 0.125f + lrel[i - j + 63];
    }
#pragma unroll
  for (int r = 0; r < 4; ++r) {
    float m = fmaxf(fmaxf(p[r], p[4 + r]), fmaxf(p[8 + r], p[12 + r]));
#pragma unroll
    for (int off = 1; off < 16; off <<= 1) m = fmaxf(m, __shfl_xor(m, off));
    float sum = 0.f;
#pragma unroll
    for (int n = 0; n < 4; ++n) {
      p[n * 4 + r] = __expf(p[n * 4 + r] - m);
      sum += p[n * 4 + r];
    }
#pragma unroll
    for (int off = 1; off < 16; off <<= 1) sum += __shfl_xor(sum, off);
    float inv = 1.0f / sum;
#pragma unroll
    for (int n = 0; n < 4; ++n) p[n * 4 + r] *= inv;
  }
#pragma unroll
  for (int n = 0; n < 4; ++n)
#pragma unroll
    for (int r = 0; r < 4; ++r)
      lP[w][(hk * 4 + r) * 64 + n * 16 + r16] = (bf16)p[n * 4 + r];
  __syncthreads();

  f32x4 o[4] = {};
#pragma unroll
  for (int ks = 0; ks < 2; ++ks) {
    bf16x8 ap = *(const bf16x8*)&lP[w][r16 * 64 + ks * 32 + hk * 8];
#pragma unroll
    for (int n = 0; n < 4; ++n) {
      bf16x8 bv_ = *(const bf16x8*)&lVt[(n * 16 + r16) * 64 + ks * 32 + hk * 8];
      o[n] = __builtin_amdgcn_mfma_f32_16x16x32_bf16(ap, bv_, o[n], 0, 0, 0);
    }
  }
#pragma unroll
  for (int n = 0; n < 4; ++n)
#pragma unroll
    for (int r = 0; r < 4; ++r) {
      int trow = b * 64 + w * 16 + hk * 4 + r;
      ctx[(size_t)trow * DMODEL + h * 64 + n * 16 + r16] = (bf16)o[n][r];
    }
}

// ---------------------------------------------------------------- layernorm
template <int F32OUT>
__global__ __launch_bounds__(256) void layernorm_k(
    const bf16* __restrict__ x, const float* __restrict__ g,
    const float* __restrict__ be, bf16* __restrict__ ob,
    float* __restrict__ of) {
  int row = blockIdx.x * 4 + (threadIdx.x >> 6);
  int lane = threadIdx.x & 63;
  const bf16* xr = x + (size_t)row * DMODEL + lane * 16;
  bf16x8 v0 = *(const bf16x8*)xr;
  bf16x8 v1 = *(const bf16x8*)(xr + 8);
  float f[16];
#pragma unroll
  for (int j = 0; j < 8; ++j) { f[j] = (float)v0[j]; f[8 + j] = (float)v1[j]; }
  float s = 0.f, sq = 0.f;
#pragma unroll
  for (int j = 0; j < 16; ++j) { s += f[j]; sq += f[j] * f[j]; }
#pragma unroll
  for (int off = 1; off < 64; off <<= 1) {
    s += __shfl_xor(s, off);
    sq += __shfl_xor(sq, off);
  }
  float mean = s * (1.0f / DMODEL);
  float var = sq * (1.0f / DMODEL) - mean * mean;
  float rstd = rsqrtf(var + 1e-5f);
  const float* gp = g + lane * 16;
  const float* bp = be + lane * 16;
  if (F32OUT) {
    float* op = of + (size_t)row * DMODEL + lane * 16;
#pragma unroll
    for (int j = 0; j < 16; ++j)
      op[j] = (f[j] - mean) * rstd * gp[j] + bp[j];
  } else {
    bf16x8 o0, o1;
#pragma unroll
    for (int j = 0; j < 8; ++j) {
      o0[j] = (bf16)((f[j] - mean) * rstd * gp[j] + bp[j]);
      o1[j] = (bf16)((f[8 + j] - mean) * rstd * gp[8 + j] + bp[8 + j]);
    }
    bf16* op = ob + (size_t)row * DMODEL + lane * 16;
    *(bf16x8*)op = o0;
    *(bf16x8*)(op + 8) = o1;
  }
}

// ---------------------------------------------------------------- launch
extern "C" void kernel_launch(void* const* d_in, const int* in_sizes, int n_in,
                              void* d_out, int out_size, void* d_ws, size_t ws_size,
                              hipStream_t stream) {
  (void)in_sizes; (void)n_in; (void)out_size;
  const float* src = (const float*)d_in[0];
  const float* Wq  = (const float*)d_in[1];
  const float* bq  = (const float*)d_in[2];
  const float* Wk  = (const float*)d_in[3];
  const float* bk  = (const float*)d_in[4];
  const float* Wv  = (const float*)d_in[5];
  const float* bv  = (const float*)d_in[6];
  const float* Wo  = (const float*)d_in[7];
  const float* bo  = (const float*)d_in[8];
  const float* rel = (const float*)d_in[9];
  const float* W1  = (const float*)d_in[10];
  const float* b1  = (const float*)d_in[11];
  const float* W2  = (const float*)d_in[12];
  const float* b2  = (const float*)d_in[13];
  const float* g1  = (const float*)d_in[14];
  const float* be1 = (const float*)d_in[15];
  const float* g2  = (const float*)d_in[16];
  const float* be2 = (const float*)d_in[17];

  // ws plan: REGION0 = ws[0:64MiB] (srcb+qb -> hbuf -> lnout);
  // weights ws[64:88MiB] (WqT/WkT/WvT contiguous => fused QKV B matrix);
  // y2 in ws[88:120MiB] when ws_size allows, else d_out + copy-out.
  char* ws = (char*)d_ws;
  const size_t MiB = 1ull << 20;
  bf16* srcb = (bf16*)(ws + 0 * MiB);
  bf16* qb   = (bf16*)(ws + 32 * MiB);
  bf16* WqT  = (bf16*)(ws + 64 * MiB);   // [3072][1024] fused: Wq|Wk|Wv
  bf16* WkT  = (bf16*)(ws + 66 * MiB);
  bf16* WvT  = (bf16*)(ws + 68 * MiB);
  bf16* WoT  = (bf16*)(ws + 70 * MiB);
  bf16* W1T  = (bf16*)(ws + 72 * MiB);
  bf16* W2T  = (bf16*)(ws + 80 * MiB);
  bf16* hbuf = (bf16*)(ws + 0 * MiB);
  float* lnout = (float*)(ws + 0 * MiB);
  bf16* kb = (bf16*)d_out;
  bf16* vb = (bf16*)((char*)d_out + 32 * MiB);
  bf16* y1 = kb;
  bf16* xb = vb;
  const bool bigws = (ws_size >= 121 * MiB);
  bf16* y2 = bigws ? (bf16*)(ws + 88 * MiB) : kb;

  cvt_copy<<<(N_TOK * DMODEL) / 2048, 256, 0, stream>>>(src, srcb);
  dim3 tb(32, 8);
  convt4<<<dim3(32, 32, 4), tb, 0, stream>>>(Wq, Wk, Wv, Wo, WqT, WkT, WvT, WoT);
  convt<<<dim3(128, 32), tb, 0, stream>>>(W1, W1T, 1024, 4096);
  convt<<<dim3(32, 128), tb, 0, stream>>>(W2, W2T, 4096, 1024);

  // fused QKV: one GEMM, N=3072 (WqT/WkT/WvT contiguous), split outputs
  const int gQKV3 = (N_TOK / 256) * (3072 / 256);   // 64*12 = 768
  gemm_f<0, 0, 1><<<gQKV3, 512, 0, stream>>>(
      srcb, WqT, bq, bk, bv, nullptr, nullptr, qb, kb, vb, N_TOK, 3072, DMODEL);

  attn_k<<<256 * NHEAD, 256, 0, stream>>>(qb, kb, vb, rel, qb);

  // y1 = ctx @ Wo + bo + src (fp32 residual); Wo B-panel (2 MiB) is
  // L2-resident so BM=128 gemm_d has no re-fetch penalty.
  const int gWo = (N_TOK / 128) * (DMODEL / 256);   // 128*4 = 512
  gemm_d<1><<<gWo, 512, 0, stream>>>(qb, WoT, bo, src, nullptr, y1, N_TOK, DMODEL, DMODEL);
  // x = LN1(y1) -> DO1
  layernorm_k<0><<<N_TOK / 4, 256, 0, stream>>>(y1, g1, be1, xb, nullptr);

  // FFN in 2 chunks of 8192 rows; h (8192x4096 bf16 = 64 MiB) in REGION0
  const int CH = 8192;
  const int gF1 = (CH / 256) * (FDIM / 256);     // 32*16 = 512
  const int gF2 = (CH / 128) * (DMODEL / 256);   // 64*4  = 256
  for (int c = 0; c < 2; ++c) {
    const bf16* xc = xb + (size_t)c * CH * DMODEL;
    bf16* yc = y2 + (size_t)c * CH * DMODEL;
    gemm_f<0, 1, 0><<<gF1, 512, 0, stream>>>(
        xc, W1T, b1, nullptr, nullptr, nullptr, nullptr, hbuf, nullptr, nullptr, CH, FDIM, DMODEL);
    gemm_d<2><<<gF2, 512, 0, stream>>>(hbuf, W2T, b2, nullptr, xc, yc, CH, DMODEL, FDIM);
  }
  if (bigws) {
    layernorm_k<1><<<N_TOK / 4, 256, 0, stream>>>(y2, g2, be2, nullptr, (float*)d_out);
  } else {
    layernorm_k<1><<<N_TOK / 4, 256, 0, stream>>>(y2, g2, be2, nullptr, lnout);
    hipMemcpyAsync(d_out, lnout, (size_t)N_TOK * DMODEL * 4, hipMemcpyDeviceToDevice, stream);
  }
}